// Round 21
// baseline (180.766 us; speedup 1.0000x reference)
//
#include <hip/hip_runtime.h>
#include <hip/hip_bf16.h>

#define NA 8192
#define NB 2048
#define DIM 192
#define NH 4
#define DKH 48
#define TA 16
#define TB 32
#define PREC 200                       // floats per partial record (192 T + 4 l + 4 A)
#define SCALE 0.14433756729740643f     // 1/sqrt(48)
#define INVSCALE 6.928203230275509f    // sqrt(48)
#define NEGBIG 1e30f

typedef __bf16 bf16x8 __attribute__((ext_vector_type(8)));
typedef float f32x4 __attribute__((ext_vector_type(4)));

#define MFMA16(a, b, c) __builtin_amdgcn_mfma_f32_16x16x32_bf16(a, b, c, 0, 0, 0)

// async global->LDS, 16B per lane, dest = ldsbase + lane*16 (wave-uniform base)
#define GLDS(gp, lp)                                                      \
  __builtin_amdgcn_global_load_lds(                                       \
      (__attribute__((address_space(1))) void*)(const void*)(gp),         \
      (__attribute__((address_space(3))) void*)(void*)(lp), 16, 0, 0)

__device__ __forceinline__ float rsumg(float v) {
  v += __shfl_xor(v, 16, 64);
  v += __shfl_xor(v, 32, 64);
  return v;
}

// ---------------- fused prep: proj + maskdetect + woe (R16-measured, 1573 blocks) ----------------
__global__ __launch_bounds__(256) void prep_kernel(
    const float* __restrict__ a_z, const float* __restrict__ bv_z,
    const float* __restrict__ Wq, const float* __restrict__ Wk, const float* __restrict__ Wv,
    const float* __restrict__ bq, const float* __restrict__ bk, const float* __restrict__ bvb,
    const float* __restrict__ Wo, const float* __restrict__ bo,
    const void* __restrict__ maskp,
    __bf16* __restrict__ Qo, __bf16* __restrict__ Ko, __bf16* __restrict__ Vo,
    float* __restrict__ WoeT, float* __restrict__ boe, int* __restrict__ mflag)
{
  const int blk = blockIdx.x;
  const int t = threadIdx.x;

  if (blk < 1536) {
    // ================= proj =================
    __shared__ float xs[8][DIM];
    const float* src; const float* W; const float* bias; int row0; int which;
    if (blk < 1024)      { src = a_z;  W = Wq; bias = bq;  row0 = blk * 8;          which = 0; }
    else if (blk < 1280) { src = bv_z; W = Wk; bias = bk;  row0 = (blk - 1024) * 8; which = 1; }
    else                 { src = bv_z; W = Wv; bias = bvb; row0 = (blk - 1280) * 8; which = 2; }
    for (int i = t; i < 8 * 48; i += 256) {
      int r = i / 48, c = i % 48;
      ((float4*)xs[r])[c] = ((const float4*)(src + (size_t)(row0 + r) * DIM))[c];
    }
    __syncthreads();
    if (t < 192) {
      float acc[8];
      float bb = bias[t];
      #pragma unroll
      for (int r = 0; r < 8; ++r) acc[r] = bb;
      const float4* wr = (const float4*)(W + (size_t)t * DIM);
      for (int c = 0; c < 48; ++c) {
        float4 w = wr[c];
        #pragma unroll
        for (int r = 0; r < 8; ++r) {
          float4 x = ((const float4*)xs[r])[c];
          acc[r] += w.x * x.x + w.y * x.y + w.z * x.z + w.w * x.w;
        }
      }
      int h = t / 48, dd = t % 48;
      if (which == 0) {
        #pragma unroll
        for (int r = 0; r < 8; ++r)
          Qo[((size_t)(row0 + r) * 4 + h) * 64 + dd] = (__bf16)acc[r];
      } else if (which == 1) {
        #pragma unroll
        for (int r = 0; r < 8; ++r)
          Ko[((size_t)h * NB + row0 + r) * 64 + dd] = (__bf16)acc[r];
      } else {
        bf16x8 pk;
        #pragma unroll
        for (int r = 0; r < 8; ++r) pk[r] = (__bf16)acc[r];
        *(bf16x8*)(Vo + (size_t)t * NB + row0) = pk;
      }
    }
    if (which == 0) {
      for (int i = t; i < 512; i += 256) {   // zero the K-pad [48,64)
        int r = i >> 6, hh = (i >> 4) & 3, kk = i & 15;
        Qo[((size_t)(row0 + r) * 4 + hh) * 64 + 48 + kk] = (__bf16)0.f;
      }
    } else if (which == 1) {
      for (int i = t; i < 512; i += 256) {
        int r = i >> 6, hh = (i >> 4) & 3, kk = i & 15;
        Ko[((size_t)hh * NB + row0 + r) * 64 + 48 + kk] = (__bf16)0.f;
      }
    }
  } else if (blk == 1536) {
    // ================= mask detect =================
    __shared__ int fl;
    if (t == 0) fl = 0;
    __syncthreads();
    const unsigned int* mw = (const unsigned int*)maskp;
    for (int i = t; i < 1024; i += 256) {
      unsigned int v = mw[i];
      if (v == 0x3F800000u) atomicMax(&fl, 2);
      else if (v > 1u) atomicMax(&fl, 1);
    }
    __syncthreads();
    if (t == 0) *mflag = fl;
  } else {
    // ================= Wo_eff^T =================
    int i = (blk - 1537) * 256 + t;
    if (i < DIM * DKH) {
      int k = i / DKH, d = i % DKH;
      float s = 0.25f * (Wo[(size_t)d * DIM + k] + Wo[(size_t)(d + 48) * DIM + k] +
                         Wo[(size_t)(d + 96) * DIM + k] + Wo[(size_t)(d + 144) * DIM + k]);
      WoeT[k * DKH + d] = s;
    }
    if (i < DKH) boe[i] = 0.25f * (bo[i] + bo[i + 48] + bo[i + 96] + bo[i + 144]);
  }
}

// ---------------- VW = per-head V @ Woe_h ----------------
__global__ __launch_bounds__(256) void vw_kernel(
    const __bf16* __restrict__ Vt, const float* __restrict__ WoeT, __bf16* __restrict__ VWt)
{
  __shared__ float woe[DIM][DKH];
  const int t = threadIdx.x;
  for (int i = t; i < DIM * DKH / 4; i += 256)
    ((float4*)&woe[0][0])[i] = ((const float4*)WoeT)[i];
  __syncthreads();
  const int b = blockIdx.x * 16 + (t & 15);
  const int grp = t >> 4;
  const int h = grp >> 2;
  const int q = grp & 3;
  float acc[12];
  #pragma unroll
  for (int d = 0; d < 12; ++d) acc[d] = 0.f;
  for (int dp = 0; dp < DKH; ++dp) {
    float v = (float)Vt[(size_t)(h * DKH + dp) * NB + b];
    const float* wrow = &woe[h * DKH + dp][q * 12];
    #pragma unroll
    for (int d = 0; d < 12; ++d) acc[d] += v * wrow[d];
  }
  #pragma unroll
  for (int d = 0; d < 12; ++d)
    VWt[(size_t)(h * DKH + q * 12 + d) * NB + b] = (__bf16)acc[d];
}

// ---------------- fused MFMA attention: R17 body VERBATIM (measured 106 us x3) ----------------
// grid = ns * 512 blocks x 256 threads. Wave = head h. m == 0 fixed reference.
// K+VW staged via global_load_lds (wave-private, zero barriers), source
// pre-swizzle, counted vmcnt(4); acc seeded wv*INVSCALE, pt = exp(s0);
// influence aa = exp(s0+wv). DO NOT MODIFY: every deviation measured +35 us.
template<int MMODE>
__global__ __launch_bounds__(256, 4) void attn_kernel(
    const __bf16* __restrict__ Qb, const __bf16* __restrict__ Kb, const __bf16* __restrict__ VWt,
    const float* __restrict__ weight, const void* __restrict__ maskp,
    const int* __restrict__ maskflag,
    float* __restrict__ part, int tps)
{
  if (*maskflag != MMODE) return;   // wrong-mode instance: early out (grid-uniform)

  __shared__ __align__(16) __bf16 Kl[4 * 32 * 64];   // 16 KB, swizzled
  __shared__ __align__(16) __bf16 VWl[192 * 32];     // 12 KB, swizzled
  __shared__ __bf16 Ss[4][16][40];                   // 5 KB P staging

  const int t = threadIdx.x;
  const int lane = t & 63;
  const int h = t >> 6;
  const int c = lane & 15;          // actor col
  const int g = lane >> 4;
  const int g8 = g * 8;
  const int s = blockIdx.x >> 9;    // split
  const int a0 = (blockIdx.x & 511) * TA;
  const int tile0 = s * tps;
  const int tend = tile0 + tps;

  const unsigned char* m8 = (const unsigned char*)maskp;
  const float* mfp = (const float*)maskp;
  const int* m32 = (const int*)maskp;

  // Q fragment (B-operand): col a = c, k contiguous
  const __bf16* qp = Qb + ((size_t)(a0 + c) * NH + h) * 64 + g8;
  const bf16x8 qf0 = *(const bf16x8*)qp;
  const bf16x8 qf1 = *(const bf16x8*)(qp + 32);

  float lp = 0.f, Ap = 0.f;
  f32x4 o0 = {0.f,0.f,0.f,0.f}, o1 = {0.f,0.f,0.f,0.f}, o2 = {0.f,0.f,0.f,0.f};

  const size_t wrow = (size_t)(a0 + c) * NB + g * 4;

  // ---- lane-constant staging geometry (source pre-swizzle; dest linear) ----
  const int kswz = 8 * ((lane & 7) ^ ((lane >> 3) & 7));        // elements
  const int vswz = 8 * ((lane & 3) ^ ((lane >> 3) & 3));        // elements
  const size_t kgrow = (size_t)h * NB + (lane >> 3);            // + b0 per tile
  const size_t vgrow = (size_t)(h * 48 + (lane >> 2)) * NB;     // + b0 per tile
  __bf16* klw = Kl + h * 2048;      // wave's K region (4 KB)
  __bf16* vlw = VWl + h * 1536;     // wave's VW region (3 KB)

  // ---- read-side swizzled fragment offsets (lane-constant) ----
  const int swk  = 8 * (g ^ (c & 7));
  const int swk4 = 8 * ((g | 4) ^ (c & 7));
  const int swv  = 8 * (g ^ ((c >> 1) & 3));
  const __bf16* klr = Kl + h * 2048 + c * 64;
  const __bf16* vlr = VWl + (h * 48 + c) * 32 + swv;

  // ---- raw W prefetch slots (mode-specialized) ----
  float4 nw0, nw1;
  int nmx, nmy;          // mode 1
  int4 nmA, nmB;         // modes 0, 2
  {
    size_t gi = wrow + (size_t)tile0 * TB;
    nw0 = *(const float4*)(weight + gi);
    nw1 = *(const float4*)(weight + gi + 16);
    if constexpr (MMODE == 1)      { nmx = *(const int*)(m8 + gi); nmy = *(const int*)(m8 + gi + 16); }
    else if constexpr (MMODE == 2) { nmA = *(const int4*)(mfp + gi); nmB = *(const int4*)(mfp + gi + 16); }
    else                           { nmA = *(const int4*)(m32 + gi); nmB = *(const int4*)(m32 + gi + 16); }
  }

  for (int tile = tile0; tile < tend; ++tile) {
    const int b0 = tile * TB;

    // [1] stage K(t) 4 + VW(t) 3 -- async, no VGPR destinations
    {
      const __bf16* kg = Kb + (kgrow + b0) * 64 + kswz;
      GLDS(kg,            klw);
      GLDS(kg + 8 * 64,   klw + 512);
      GLDS(kg + 16 * 64,  klw + 1024);
      GLDS(kg + 24 * 64,  klw + 1536);
      const __bf16* vg = VWt + vgrow + b0 + vswz;
      GLDS(vg,            vlw);
      GLDS(vg + 16 * NB,  vlw + 512);
      GLDS(vg + 32 * NB,  vlw + 1024);
    }
    __builtin_amdgcn_sched_barrier(0);

    // [2] convert W(t) (its 4 loads are front-of-queue; compiler waits just them)
    float wv[8];
    if constexpr (MMODE == 1) {
      unsigned ua = (unsigned)nmx, ub = (unsigned)nmy;
      wv[0] = (ua & 0xffu)         ? nw0.x : -NEGBIG;
      wv[1] = ((ua >> 8) & 0xffu)  ? nw0.y : -NEGBIG;
      wv[2] = ((ua >> 16) & 0xffu) ? nw0.z : -NEGBIG;
      wv[3] = (ua >> 24)           ? nw0.w : -NEGBIG;
      wv[4] = (ub & 0xffu)         ? nw1.x : -NEGBIG;
      wv[5] = ((ub >> 8) & 0xffu)  ? nw1.y : -NEGBIG;
      wv[6] = ((ub >> 16) & 0xffu) ? nw1.z : -NEGBIG;
      wv[7] = (ub >> 24)           ? nw1.w : -NEGBIG;
    } else if constexpr (MMODE == 2) {
      wv[0] = (((unsigned)nmA.x << 1) != 0u) ? nw0.x : -NEGBIG;
      wv[1] = (((unsigned)nmA.y << 1) != 0u) ? nw0.y : -NEGBIG;
      wv[2] = (((unsigned)nmA.z << 1) != 0u) ? nw0.z : -NEGBIG;
      wv[3] = (((unsigned)nmA.w << 1) != 0u) ? nw0.w : -NEGBIG;
      wv[4] = (((unsigned)nmB.x << 1) != 0u) ? nw1.x : -NEGBIG;
      wv[5] = (((unsigned)nmB.y << 1) != 0u) ? nw1.y : -NEGBIG;
      wv[6] = (((unsigned)nmB.z << 1) != 0u) ? nw1.z : -NEGBIG;
      wv[7] = (((unsigned)nmB.w << 1) != 0u) ? nw1.w : -NEGBIG;
    } else {
      wv[0] = nmA.x ? nw0.x : -NEGBIG;
      wv[1] = nmA.y ? nw0.y : -NEGBIG;
      wv[2] = nmA.z ? nw0.z : -NEGBIG;
      wv[3] = nmA.w ? nw0.w : -NEGBIG;
      wv[4] = nmB.x ? nw1.x : -NEGBIG;
      wv[5] = nmB.y ? nw1.y : -NEGBIG;
      wv[6] = nmB.z ? nw1.z : -NEGBIG;
      wv[7] = nmB.w ? nw1.w : -NEGBIG;
    }
    __builtin_amdgcn_sched_barrier(0);

    // [3] issue W(t+1) raws (behind stages in FIFO)
    {
      int tn = (tile + 1 < tend) ? tile + 1 : tile;
      size_t gi = wrow + (size_t)tn * TB;
      nw0 = *(const float4*)(weight + gi);
      nw1 = *(const float4*)(weight + gi + 16);
      if constexpr (MMODE == 1)      { nmx = *(const int*)(m8 + gi); nmy = *(const int*)(m8 + gi + 16); }
      else if constexpr (MMODE == 2) { nmA = *(const int4*)(mfp + gi); nmB = *(const int4*)(mfp + gi + 16); }
      else                           { nmA = *(const int4*)(m32 + gi); nmB = *(const int4*)(m32 + gi + 16); }
    }
    __builtin_amdgcn_sched_barrier(0);

    // [4] counted wait: drain the 7 stages, leave W(t+1)'s 4 loads in flight
    asm volatile("s_waitcnt vmcnt(4)" ::: "memory");
    __builtin_amdgcn_sched_barrier(0);

    // [5] fragments from LDS (swizzled, conflict-free) + compute
    bf16x8 kA0 = *(const bf16x8*)(klr + swk);
    bf16x8 kA1 = *(const bf16x8*)(klr + swk4);
    bf16x8 kB0 = *(const bf16x8*)(klr + 16 * 64 + swk);
    bf16x8 kB1 = *(const bf16x8*)(klr + 16 * 64 + swk4);
    bf16x8 vf0 = *(const bf16x8*)vlr;
    bf16x8 vf1 = *(const bf16x8*)(vlr + 16 * 32);
    bf16x8 vf2 = *(const bf16x8*)(vlr + 32 * 32);

    f32x4 acc0, acc1;
    #pragma unroll
    for (int j = 0; j < 4; ++j) { acc0[j] = wv[j] * INVSCALE; acc1[j] = wv[4 + j] * INVSCALE; }
    acc0 = MFMA16(kA0, qf0, acc0);
    acc0 = MFMA16(kA1, qf1, acc0);
    acc1 = MFMA16(kB0, qf0, acc1);
    acc1 = MFMA16(kB1, qf1, acc1);

    float p[8];
    #pragma unroll
    for (int j = 0; j < 4; ++j) {
      float s0 = acc0[j] * SCALE, s1 = acc1[j] * SCALE;
      float p0 = __expf(s0), p1 = __expf(s1);
      lp += p0 + p1;
      Ap += __expf(s0 + wv[j]) + __expf(s1 + wv[4 + j]);
      p[j] = p0; p[4 + j] = p1;
    }

    #pragma unroll
    for (int i = 0; i < 4; ++i) {
      Ss[h][c][g * 4 + i]      = (__bf16)p[i];
      Ss[h][c][16 + g * 4 + i] = (__bf16)p[4 + i];
    }
    __builtin_amdgcn_sched_barrier(0);
    bf16x8 pb = *(const bf16x8*)&Ss[h][c][g8];

    o0 = MFMA16(vf0, pb, o0);
    o1 = MFMA16(vf1, pb, o1);
    o2 = MFMA16(vf2, pb, o2);
  }

  // ---- one wave-reduce at the end; write partial record ----
  float l = rsumg(lp);
  float A = rsumg(Ap);
  float* pr = part + ((size_t)s * NA + a0 + c) * PREC;
  #pragma unroll
  for (int j = 0; j < 4; ++j) {
    pr[h * 48 + g * 4 + j]      = o0[j];
    pr[h * 48 + 16 + g * 4 + j] = o1[j];
    pr[h * 48 + 32 + g * 4 + j] = o2[j];
  }
  if (g == 0) {
    pr[192 + h] = l;
    pr[196 + h] = A;
  }
}

// ---------------- merge: block-local Lw stream + plain-sum merge ----------------
// grid = NA/8 = 1024 blocks x 256 threads; 8 actors/block.
// Phase 1: each wave streams 2 weight rows (mask-gated exp-sum) -> lws[8] in LDS.
// Phase 2: influence + topic_align (plain sums, m == 0 scheme).
__global__ __launch_bounds__(256) void merge_kernel(
    const float* __restrict__ part, const float* __restrict__ weight,
    const void* __restrict__ maskp, const int* __restrict__ maskflag,
    const float* __restrict__ boe, float* __restrict__ out, int ns)
{
  __shared__ float lws[8];
  __shared__ float fls[8][NH];
  __shared__ float infl[8][NH];
  const int t = threadIdx.x;
  const int lane = t & 63;
  const int w = t >> 6;
  const int a0 = blockIdx.x * 8;
  const int mmode = *maskflag;
  const unsigned char* m8 = (const unsigned char*)maskp;
  const float* mf = (const float*)maskp;
  const int* m32 = (const int*)maskp;

  // ---- phase 1: Lw for this block's 8 actors (wave w -> actors 2w, 2w+1) ----
  #pragma unroll
  for (int k = 0; k < 2; ++k) {
    const int a = a0 + w * 2 + k;
    const float* wr = weight + (size_t)a * NB;
    const size_t mb = (size_t)a * NB;
    float sloc = 0.f;
    #pragma unroll
    for (int it = 0; it < 8; ++it) {
      int idx = it * 256 + lane * 4;
      float4 w4 = *(const float4*)(wr + idx);
      bool ok0, ok1, ok2, ok3;
      if (mmode == 1) {
        unsigned mm = *(const unsigned*)(m8 + mb + idx);
        ok0 = mm & 0xffu; ok1 = (mm >> 8) & 0xffu; ok2 = (mm >> 16) & 0xffu; ok3 = mm >> 24;
      } else if (mmode == 2) {
        float4 mv = *(const float4*)(mf + mb + idx);
        ok0 = mv.x != 0.f; ok1 = mv.y != 0.f; ok2 = mv.z != 0.f; ok3 = mv.w != 0.f;
      } else {
        int4 mv = *(const int4*)(m32 + mb + idx);
        ok0 = mv.x; ok1 = mv.y; ok2 = mv.z; ok3 = mv.w;
      }
      float e0 = ok0 ? __expf(w4.x) : 0.f;
      float e1 = ok1 ? __expf(w4.y) : 0.f;
      float e2 = ok2 ? __expf(w4.z) : 0.f;
      float e3 = ok3 ? __expf(w4.w) : 0.f;
      sloc += (e0 + e1) + (e2 + e3);
    }
    #pragma unroll
    for (int off = 1; off < 64; off <<= 1) sloc += __shfl_xor(sloc, off, 64);
    if (lane == 0) lws[w * 2 + k] = sloc;
  }
  __syncthreads();

  // ---- phase 2a: per-(a,h) stats ----
  if (t < 32) {
    int a = t >> 2, hh = t & 3;
    const float* rec = part + (size_t)(a0 + a) * PREC;
    float lst = 0.f, As = 0.f;
    for (int s = 0; s < ns; ++s) {
      const float* r = rec + (size_t)s * NA * PREC;
      lst += r[192 + hh];
      As  += r[196 + hh];
    }
    float li = 1.f / lst;
    fls[a][hh] = li;
    infl[a][hh] = As * li;
  }
  __syncthreads();
  if (t < 8)
    out[(size_t)(a0 + t) * 49 + 48] =
        (infl[t][0] + infl[t][1] + infl[t][2] + infl[t][3]) / (4.f * lws[t]);

  // ---- phase 2b: topic_align ----
  for (int i = t; i < 8 * DKH; i += 256) {
    int a = i / DKH, dd = i - a * DKH;
    float acc = boe[dd];
    const float* rec = part + (size_t)(a0 + a) * PREC;
    for (int s = 0; s < ns; ++s) {
      const float* r = rec + (size_t)s * NA * PREC;
      #pragma unroll
      for (int hh = 0; hh < NH; ++hh)
        acc += fls[a][hh] * r[hh * 48 + dd];
    }
    out[(size_t)(a0 + a) * 49 + dd] = acc;
  }
}

extern "C" void kernel_launch(void* const* d_in, const int* in_sizes, int n_in,
                              void* d_out, int out_size, void* d_ws, size_t ws_size,
                              hipStream_t stream) {
  const float* a_z    = (const float*)d_in[0];
  const float* bv_z   = (const float*)d_in[1];
  const float* weight = (const float*)d_in[2];
  const void*  maskp  = d_in[3];
  const float* Wq = (const float*)d_in[4];
  const float* Wk = (const float*)d_in[5];
  const float* Wv = (const float*)d_in[6];
  const float* Wo = (const float*)d_in[7];
  const float* bq = (const float*)d_in[8];
  const float* bk = (const float*)d_in[9];
  const float* bvb = (const float*)d_in[10];
  const float* bo = (const float*)d_in[11];

  __bf16* Qb  = (__bf16*)d_ws;                      // [NA][4][64]
  __bf16* Kb  = Qb + (size_t)NA * 256;              // [4][NB][64]
  __bf16* Vtg = Kb + (size_t)4 * NB * 64;           // [192][NB]
  __bf16* VWt = Vtg + (size_t)DIM * NB;             // [192][NB]
  float* WoeT = (float*)(VWt + (size_t)DIM * NB);   // [192][48]
  float* boe  = WoeT + DIM * DKH;
  int*  mflag = (int*)(boe + 64);
  float* part = (float*)(mflag + 64);               // [ns][NA][200]

  size_t base = (size_t)((char*)(part) - (char*)d_ws);
  int ns = (ws_size >= base + (size_t)4 * NA * PREC * 4) ? 4 : 2;
  int tps = (NB / TB) / ns;

  prep_kernel<<<1573, 256, 0, stream>>>(a_z, bv_z, Wq, Wk, Wv, bq, bk, bvb, Wo, bo,
                                        maskp, Qb, Kb, Vtg, WoeT, boe, mflag);
  vw_kernel<<<NB / 16, 256, 0, stream>>>(Vtg, WoeT, VWt);
  attn_kernel<1><<<ns * 512, 256, 0, stream>>>(Qb, Kb, VWt, weight, maskp, mflag, part, tps);
  attn_kernel<0><<<ns * 512, 256, 0, stream>>>(Qb, Kb, VWt, weight, maskp, mflag, part, tps);
  attn_kernel<2><<<ns * 512, 256, 0, stream>>>(Qb, Kb, VWt, weight, maskp, mflag, part, tps);
  merge_kernel<<<NA / 8, 256, 0, stream>>>(part, weight, maskp, mflag, boe, (float*)d_out, ns);
}

// Round 22
// 173.493 us; speedup vs baseline: 1.0419x; 1.0419x over previous
//
#include <hip/hip_runtime.h>
#include <hip/hip_bf16.h>

#define NA 8192
#define NB 2048
#define DIM 192
#define NH 4
#define DKH 48
#define TA 16
#define TB 32
#define PREC 204                       // floats per partial record (192 T + 4 l + 4 A + Lw + pad)
#define SCALE 0.14433756729740643f     // 1/sqrt(48)
#define NEGBIG 1e30f

typedef __bf16 bf16x8 __attribute__((ext_vector_type(8)));
typedef float f32x4 __attribute__((ext_vector_type(4)));

#define MFMA16(a, b, c) __builtin_amdgcn_mfma_f32_16x16x32_bf16(a, b, c, 0, 0, 0)

// async global->LDS, 16B per lane, dest = ldsbase + lane*16 (wave-uniform base)
#define GLDS(gp, lp)                                                      \
  __builtin_amdgcn_global_load_lds(                                       \
      (__attribute__((address_space(1))) void*)(const void*)(gp),         \
      (__attribute__((address_space(3))) void*)(void*)(lp), 16, 0, 0)

__device__ __forceinline__ float rsumg(float v) {
  v += __shfl_xor(v, 16, 64);
  v += __shfl_xor(v, 32, 64);
  return v;
}

// ---------------- fused prep: proj + maskdetect + woe ----------------
// blocks [0,1536): Q/K/V projections; 1536: mask detect; [1537,1573): Wo_eff^T
__global__ __launch_bounds__(256) void prep_kernel(
    const float* __restrict__ a_z, const float* __restrict__ bv_z,
    const float* __restrict__ Wq, const float* __restrict__ Wk, const float* __restrict__ Wv,
    const float* __restrict__ bq, const float* __restrict__ bk, const float* __restrict__ bvb,
    const float* __restrict__ Wo, const float* __restrict__ bo,
    const void* __restrict__ maskp,
    __bf16* __restrict__ Qo, __bf16* __restrict__ Ko, __bf16* __restrict__ Vo,
    float* __restrict__ WoeT, float* __restrict__ boe, int* __restrict__ mflag)
{
  const int blk = blockIdx.x;
  const int t = threadIdx.x;

  if (blk < 1536) {
    // ================= proj =================
    __shared__ float xs[8][DIM];
    const float* src; const float* W; const float* bias; int row0; int which;
    if (blk < 1024)      { src = a_z;  W = Wq; bias = bq;  row0 = blk * 8;          which = 0; }
    else if (blk < 1280) { src = bv_z; W = Wk; bias = bk;  row0 = (blk - 1024) * 8; which = 1; }
    else                 { src = bv_z; W = Wv; bias = bvb; row0 = (blk - 1280) * 8; which = 2; }
    for (int i = t; i < 8 * 48; i += 256) {
      int r = i / 48, c = i % 48;
      ((float4*)xs[r])[c] = ((const float4*)(src + (size_t)(row0 + r) * DIM))[c];
    }
    __syncthreads();
    if (t < 192) {
      float acc[8];
      float bb = bias[t];
      #pragma unroll
      for (int r = 0; r < 8; ++r) acc[r] = bb;
      const float4* wr = (const float4*)(W + (size_t)t * DIM);
      for (int c = 0; c < 48; ++c) {
        float4 w = wr[c];
        #pragma unroll
        for (int r = 0; r < 8; ++r) {
          float4 x = ((const float4*)xs[r])[c];
          acc[r] += w.x * x.x + w.y * x.y + w.z * x.z + w.w * x.w;
        }
      }
      int h = t / 48, dd = t % 48;
      if (which == 0) {
        #pragma unroll
        for (int r = 0; r < 8; ++r)
          Qo[((size_t)(row0 + r) * 4 + h) * 64 + dd] = (__bf16)acc[r];
      } else if (which == 1) {
        #pragma unroll
        for (int r = 0; r < 8; ++r)
          Ko[((size_t)h * NB + row0 + r) * 64 + dd] = (__bf16)acc[r];
      } else {
        bf16x8 pk;
        #pragma unroll
        for (int r = 0; r < 8; ++r) pk[r] = (__bf16)acc[r];
        *(bf16x8*)(Vo + (size_t)t * NB + row0) = pk;
      }
    }
    if (which == 0) {
      for (int i = t; i < 512; i += 256) {   // zero the K-pad [48,64)
        int r = i >> 6, hh = (i >> 4) & 3, kk = i & 15;
        Qo[((size_t)(row0 + r) * 4 + hh) * 64 + 48 + kk] = (__bf16)0.f;
      }
    } else if (which == 1) {
      for (int i = t; i < 512; i += 256) {
        int r = i >> 6, hh = (i >> 4) & 3, kk = i & 15;
        Ko[((size_t)hh * NB + row0 + r) * 64 + 48 + kk] = (__bf16)0.f;
      }
    }
  } else if (blk == 1536) {
    // ================= mask detect =================
    __shared__ int fl;
    if (t == 0) fl = 0;
    __syncthreads();
    const unsigned int* mw = (const unsigned int*)maskp;
    for (int i = t; i < 1024; i += 256) {
      unsigned int v = mw[i];
      if (v == 0x3F800000u) atomicMax(&fl, 2);
      else if (v > 1u) atomicMax(&fl, 1);
    }
    __syncthreads();
    if (t == 0) *mflag = fl;
  } else {
    // ================= Wo_eff^T =================
    int i = (blk - 1537) * 256 + t;
    if (i < DIM * DKH) {
      int k = i / DKH, d = i % DKH;
      float s = 0.25f * (Wo[(size_t)d * DIM + k] + Wo[(size_t)(d + 48) * DIM + k] +
                         Wo[(size_t)(d + 96) * DIM + k] + Wo[(size_t)(d + 144) * DIM + k]);
      WoeT[k * DKH + d] = s;
    }
    if (i < DKH) boe[i] = 0.25f * (bo[i] + bo[i + 48] + bo[i + 96] + bo[i + 144]);
  }
}

// ---------------- VW = per-head V @ Woe_h ----------------
__global__ __launch_bounds__(256) void vw_kernel(
    const __bf16* __restrict__ Vt, const float* __restrict__ WoeT, __bf16* __restrict__ VWt)
{
  __shared__ float woe[DIM][DKH];
  const int t = threadIdx.x;
  for (int i = t; i < DIM * DKH / 4; i += 256)
    ((float4*)&woe[0][0])[i] = ((const float4*)WoeT)[i];
  __syncthreads();
  const int b = blockIdx.x * 16 + (t & 15);
  const int grp = t >> 4;
  const int h = grp >> 2;
  const int q = grp & 3;
  float acc[12];
  #pragma unroll
  for (int d = 0; d < 12; ++d) acc[d] = 0.f;
  for (int dp = 0; dp < DKH; ++dp) {
    float v = (float)Vt[(size_t)(h * DKH + dp) * NB + b];
    const float* wrow = &woe[h * DKH + dp][q * 12];
    #pragma unroll
    for (int d = 0; d < 12; ++d) acc[d] += v * wrow[d];
  }
  #pragma unroll
  for (int d = 0; d < 12; ++d)
    VWt[(size_t)(h * DKH + q * 12 + d) * NB + b] = (__bf16)acc[d];
}

// ---------------- fused MFMA attention: R16 body + DEPTH-2 weight prefetch ----------------
// grid = ns * 512 blocks x 256 threads. Wave = head h. m == 0 fixed reference.
// ew-factored softmax (R16): ew = mask ? exp(w) : 0; QK seeds ZERO; p = exp(qk)*ew;
// Ap += p*ew; Lw = sum(ew) (free). K+VW via global_load_lds, source pre-swizzle.
// NEW: W prefetched TWO tiles ahead (two named slot sets, x2-unrolled loop) so the
// ~900cy cold-HBM weight latency is covered without an L3 pre-warming pass.
// Steady-state FIFO at [4]: [W(t+1) 4][stages 7][W(t+2) 4]; vmcnt(4) retires
// W(t+1) (>=1.5 bodies old) + stages, leaves W(t+2) in flight; convert at body
// t+1 then never waits.
template<int MMODE>
__global__ __launch_bounds__(256, 4) void attn_kernel(
    const __bf16* __restrict__ Qb, const __bf16* __restrict__ Kb, const __bf16* __restrict__ VWt,
    const float* __restrict__ weight, const void* __restrict__ maskp,
    const int* __restrict__ maskflag,
    float* __restrict__ part, int tps)
{
  if (*maskflag != MMODE) return;   // wrong-mode instance: early out (grid-uniform)

  __shared__ __align__(16) __bf16 Kl[4 * 32 * 64];   // 16 KB, swizzled
  __shared__ __align__(16) __bf16 VWl[192 * 32];     // 12 KB, swizzled
  __shared__ __bf16 Ss[4][16][40];                   // 5 KB P staging

  const int t = threadIdx.x;
  const int lane = t & 63;
  const int h = t >> 6;
  const int c = lane & 15;          // actor col
  const int g = lane >> 4;
  const int g8 = g * 8;
  const int s = blockIdx.x >> 9;    // split
  const int a0 = (blockIdx.x & 511) * TA;
  const int tile0 = s * tps;
  const int tend = tile0 + tps;     // tps even (16 or 32)

  const unsigned char* m8 = (const unsigned char*)maskp;
  const float* mfp = (const float*)maskp;
  const int* m32 = (const int*)maskp;

  // Q fragment (B-operand): col a = c, k contiguous
  const __bf16* qp = Qb + ((size_t)(a0 + c) * NH + h) * 64 + g8;
  const bf16x8 qf0 = *(const bf16x8*)qp;
  const bf16x8 qf1 = *(const bf16x8*)(qp + 32);

  float lp = 0.f, Ap = 0.f, Lwp = 0.f;
  f32x4 o0 = {0.f,0.f,0.f,0.f}, o1 = {0.f,0.f,0.f,0.f}, o2 = {0.f,0.f,0.f,0.f};

  const size_t wrow = (size_t)(a0 + c) * NB + g * 4;

  // ---- lane-constant staging geometry (source pre-swizzle; dest linear) ----
  const int kswz = 8 * ((lane & 7) ^ ((lane >> 3) & 7));        // elements
  const int vswz = 8 * ((lane & 3) ^ ((lane >> 3) & 3));        // elements
  const size_t kgrow = (size_t)h * NB + (lane >> 3);            // + b0 per tile
  const size_t vgrow = (size_t)(h * 48 + (lane >> 2)) * NB;     // + b0 per tile
  __bf16* klw = Kl + h * 2048;      // wave's K region (4 KB)
  __bf16* vlw = VWl + h * 1536;     // wave's VW region (3 KB)

  // ---- read-side swizzled fragment offsets (lane-constant) ----
  const int swk  = 8 * (g ^ (c & 7));
  const int swk4 = 8 * ((g | 4) ^ (c & 7));
  const int swv  = 8 * (g ^ ((c >> 1) & 3));
  const __bf16* klr = Kl + h * 2048 + c * 64;
  const __bf16* vlr = VWl + (h * 48 + c) * 32 + swv;

  // ---- two named W prefetch slot sets (depth-2 ring; rule #20: no runtime idx) ----
  float4 nw0a, nw1a, nw0b, nw1b;
  int nmxa, nmya, nmxb, nmyb;        // mode 1
  int4 nmAa, nmBa, nmAb, nmBb;       // modes 0, 2

#define ISSUE_W(T, W0, W1, MX, MY, MA, MB)                                        \
  do {                                                                            \
    size_t gi = wrow + (size_t)(T) * TB;                                          \
    W0 = *(const float4*)(weight + gi);                                           \
    W1 = *(const float4*)(weight + gi + 16);                                      \
    if constexpr (MMODE == 1)      { MX = *(const int*)(m8 + gi);                 \
                                     MY = *(const int*)(m8 + gi + 16); }          \
    else if constexpr (MMODE == 2) { MA = *(const int4*)(mfp + gi);               \
                                     MB = *(const int4*)(mfp + gi + 16); }        \
    else                           { MA = *(const int4*)(m32 + gi);               \
                                     MB = *(const int4*)(m32 + gi + 16); }        \
  } while (0)

#define CONVERT_EW(EW, W0, W1, MX, MY, MA, MB)                                    \
  do {                                                                            \
    if constexpr (MMODE == 1) {                                                   \
      unsigned ua = (unsigned)MX, ub = (unsigned)MY;                              \
      EW[0] = (ua & 0xffu)         ? __expf(W0.x) : 0.f;                          \
      EW[1] = ((ua >> 8) & 0xffu)  ? __expf(W0.y) : 0.f;                          \
      EW[2] = ((ua >> 16) & 0xffu) ? __expf(W0.z) : 0.f;                          \
      EW[3] = (ua >> 24)           ? __expf(W0.w) : 0.f;                          \
      EW[4] = (ub & 0xffu)         ? __expf(W1.x) : 0.f;                          \
      EW[5] = ((ub >> 8) & 0xffu)  ? __expf(W1.y) : 0.f;                          \
      EW[6] = ((ub >> 16) & 0xffu) ? __expf(W1.z) : 0.f;                          \
      EW[7] = (ub >> 24)           ? __expf(W1.w) : 0.f;                          \
    } else if constexpr (MMODE == 2) {                                            \
      EW[0] = (((unsigned)MA.x << 1) != 0u) ? __expf(W0.x) : 0.f;                 \
      EW[1] = (((unsigned)MA.y << 1) != 0u) ? __expf(W0.y) : 0.f;                 \
      EW[2] = (((unsigned)MA.z << 1) != 0u) ? __expf(W0.z) : 0.f;                 \
      EW[3] = (((unsigned)MA.w << 1) != 0u) ? __expf(W0.w) : 0.f;                 \
      EW[4] = (((unsigned)MB.x << 1) != 0u) ? __expf(W1.x) : 0.f;                 \
      EW[5] = (((unsigned)MB.y << 1) != 0u) ? __expf(W1.y) : 0.f;                 \
      EW[6] = (((unsigned)MB.z << 1) != 0u) ? __expf(W1.z) : 0.f;                 \
      EW[7] = (((unsigned)MB.w << 1) != 0u) ? __expf(W1.w) : 0.f;                 \
    } else {                                                                      \
      EW[0] = MA.x ? __expf(W0.x) : 0.f;                                          \
      EW[1] = MA.y ? __expf(W0.y) : 0.f;                                          \
      EW[2] = MA.z ? __expf(W0.z) : 0.f;                                          \
      EW[3] = MA.w ? __expf(W0.w) : 0.f;                                          \
      EW[4] = MB.x ? __expf(W1.x) : 0.f;                                          \
      EW[5] = MB.y ? __expf(W1.y) : 0.f;                                          \
      EW[6] = MB.z ? __expf(W1.z) : 0.f;                                          \
      EW[7] = MB.w ? __expf(W1.w) : 0.f;                                          \
    }                                                                             \
  } while (0)

  // BODY(tile, slot regs): [1] stage; [2] convert ew (no wait in steady state);
  // [3] reissue slot for tile+2; [4] vmcnt(4); [5] compute (R16 body).
#define BODY(TILE, W0, W1, MX, MY, MA, MB)                                        \
  do {                                                                            \
    const int tile_ = (TILE);                                                     \
    const int b0 = tile_ * TB;                                                    \
    {                                                                             \
      const __bf16* kg = Kb + (kgrow + b0) * 64 + kswz;                           \
      GLDS(kg,            klw);                                                   \
      GLDS(kg + 8 * 64,   klw + 512);                                             \
      GLDS(kg + 16 * 64,  klw + 1024);                                            \
      GLDS(kg + 24 * 64,  klw + 1536);                                            \
      const __bf16* vg = VWt + vgrow + b0 + vswz;                                 \
      GLDS(vg,            vlw);                                                   \
      GLDS(vg + 16 * NB,  vlw + 512);                                             \
      GLDS(vg + 32 * NB,  vlw + 1024);                                            \
    }                                                                             \
    __builtin_amdgcn_sched_barrier(0);                                            \
    float ew[8];                                                                  \
    CONVERT_EW(ew, W0, W1, MX, MY, MA, MB);                                       \
    __builtin_amdgcn_sched_barrier(0);                                            \
    {                                                                             \
      int tn = (tile_ + 2 < tend) ? tile_ + 2 : tend - 1;                         \
      ISSUE_W(tn, W0, W1, MX, MY, MA, MB);                                        \
    }                                                                             \
    __builtin_amdgcn_sched_barrier(0);                                            \
    asm volatile("s_waitcnt vmcnt(4)" ::: "memory");                              \
    __builtin_amdgcn_sched_barrier(0);                                            \
    bf16x8 kA0 = *(const bf16x8*)(klr + swk);                                     \
    bf16x8 kA1 = *(const bf16x8*)(klr + swk4);                                    \
    bf16x8 kB0 = *(const bf16x8*)(klr + 16 * 64 + swk);                           \
    bf16x8 kB1 = *(const bf16x8*)(klr + 16 * 64 + swk4);                          \
    bf16x8 vf0 = *(const bf16x8*)vlr;                                             \
    bf16x8 vf1 = *(const bf16x8*)(vlr + 16 * 32);                                 \
    bf16x8 vf2 = *(const bf16x8*)(vlr + 32 * 32);                                 \
    f32x4 acc0 = {0.f,0.f,0.f,0.f}, acc1 = {0.f,0.f,0.f,0.f};                     \
    acc0 = MFMA16(kA0, qf0, acc0);                                                \
    acc0 = MFMA16(kA1, qf1, acc0);                                                \
    acc1 = MFMA16(kB0, qf0, acc1);                                                \
    acc1 = MFMA16(kB1, qf1, acc1);                                                \
    Lwp += (ew[0] + ew[1]) + (ew[2] + ew[3]) + (ew[4] + ew[5]) + (ew[6] + ew[7]); \
    float pt[8];                                                                  \
    _Pragma("unroll")                                                             \
    for (int j = 0; j < 4; ++j) {                                                 \
      float e0 = __expf(acc0[j] * SCALE);                                         \
      float e1 = __expf(acc1[j] * SCALE);                                         \
      float p0 = e0 * ew[j];                                                      \
      float p1 = e1 * ew[4 + j];                                                  \
      lp += p0 + p1;                                                              \
      Ap += p0 * ew[j] + p1 * ew[4 + j];                                          \
      pt[j] = p0; pt[4 + j] = p1;                                                 \
    }                                                                             \
    _Pragma("unroll")                                                             \
    for (int i = 0; i < 4; ++i) {                                                 \
      Ss[h][c][g * 4 + i]      = (__bf16)pt[i];                                   \
      Ss[h][c][16 + g * 4 + i] = (__bf16)pt[4 + i];                               \
    }                                                                             \
    __builtin_amdgcn_sched_barrier(0);                                            \
    bf16x8 pb = *(const bf16x8*)&Ss[h][c][g8];                                    \
    o0 = MFMA16(vf0, pb, o0);                                                     \
    o1 = MFMA16(vf1, pb, o1);                                                     \
    o2 = MFMA16(vf2, pb, o2);                                                     \
  } while (0)

  // prologue: issue W(tile0) -> slot A, W(tile0+1) -> slot B
  ISSUE_W(tile0,     nw0a, nw1a, nmxa, nmya, nmAa, nmBa);
  ISSUE_W(tile0 + 1, nw0b, nw1b, nmxb, nmyb, nmAb, nmBb);

  for (int tile = tile0; tile < tend; tile += 2) {
    BODY(tile,     nw0a, nw1a, nmxa, nmya, nmAa, nmBa);
    BODY(tile + 1, nw0b, nw1b, nmxb, nmyb, nmAb, nmBb);
  }

  // ---- one wave-reduce at the end; write partial record ----
  float l = rsumg(lp);
  float A = rsumg(Ap);
  float Lw = rsumg(Lwp);
  float* pr = part + ((size_t)s * NA + a0 + c) * PREC;
  #pragma unroll
  for (int j = 0; j < 4; ++j) {
    pr[h * 48 + g * 4 + j]      = o0[j];
    pr[h * 48 + 16 + g * 4 + j] = o1[j];
    pr[h * 48 + 32 + g * 4 + j] = o2[j];
  }
  if (g == 0) {
    pr[192 + h] = l;
    pr[196 + h] = A;
    if (h == 0) pr[200] = Lw;
  }
#undef ISSUE_W
#undef CONVERT_EW
#undef BODY
}

// ---------------- merge splits: plain sums (shared m == 0 reference) ----------------
__global__ __launch_bounds__(256) void merge_kernel(
    const float* __restrict__ part, const float* __restrict__ boe,
    float* __restrict__ out, int ns)
{
  __shared__ float fls[32][NH];      // 1/l per (a,h)
  __shared__ float infl[32][NH];
  __shared__ float lws[32];
  const int t = threadIdx.x;
  const int a0 = blockIdx.x * 32;

  if (t < 128) {
    int a = t >> 2, hh = t & 3;
    const float* rec = part + (size_t)(a0 + a) * PREC;
    float lst = 0.f, As = 0.f, Lws = 0.f;
    for (int s = 0; s < ns; ++s) {
      const float* r = rec + (size_t)s * NA * PREC;
      lst += r[192 + hh];
      As  += r[196 + hh];
      if (hh == 0) Lws += r[200];
    }
    float li = 1.f / lst;
    fls[a][hh] = li;
    infl[a][hh] = As * li;
    if (hh == 0) lws[a] = Lws;
  }
  __syncthreads();
  if (t < 32)
    out[(size_t)(a0 + t) * 49 + 48] =
        (infl[t][0] + infl[t][1] + infl[t][2] + infl[t][3]) / (4.f * lws[t]);
  for (int i = t; i < 32 * DKH; i += 256) {
    int a = i / DKH, dd = i - a * DKH;
    float acc = boe[dd];
    const float* rec = part + (size_t)(a0 + a) * PREC;
    for (int s = 0; s < ns; ++s) {
      const float* r = rec + (size_t)s * NA * PREC;
      #pragma unroll
      for (int hh = 0; hh < NH; ++hh)
        acc += fls[a][hh] * r[hh * 48 + dd];
    }
    out[(size_t)(a0 + a) * 49 + dd] = acc;
  }
}

extern "C" void kernel_launch(void* const* d_in, const int* in_sizes, int n_in,
                              void* d_out, int out_size, void* d_ws, size_t ws_size,
                              hipStream_t stream) {
  const float* a_z    = (const float*)d_in[0];
  const float* bv_z   = (const float*)d_in[1];
  const float* weight = (const float*)d_in[2];
  const void*  maskp  = d_in[3];
  const float* Wq = (const float*)d_in[4];
  const float* Wk = (const float*)d_in[5];
  const float* Wv = (const float*)d_in[6];
  const float* Wo = (const float*)d_in[7];
  const float* bq = (const float*)d_in[8];
  const float* bk = (const float*)d_in[9];
  const float* bvb = (const float*)d_in[10];
  const float* bo = (const float*)d_in[11];

  __bf16* Qb  = (__bf16*)d_ws;                      // [NA][4][64]
  __bf16* Kb  = Qb + (size_t)NA * 256;              // [4][NB][64]
  __bf16* Vtg = Kb + (size_t)4 * NB * 64;           // [192][NB]
  __bf16* VWt = Vtg + (size_t)DIM * NB;             // [192][NB]
  float* WoeT = (float*)(VWt + (size_t)DIM * NB);   // [192][48]
  float* boe  = WoeT + DIM * DKH;
  int*  mflag = (int*)(boe + 64);
  float* part = (float*)(mflag + 64);               // [ns][NA][204]

  size_t base = (size_t)((char*)(part) - (char*)d_ws);
  int ns = (ws_size >= base + (size_t)4 * NA * PREC * 4) ? 4 : 2;
  int tps = (NB / TB) / ns;

  prep_kernel<<<1573, 256, 0, stream>>>(a_z, bv_z, Wq, Wk, Wv, bq, bk, bvb, Wo, bo,
                                        maskp, Qb, Kb, Vtg, WoeT, boe, mflag);
  vw_kernel<<<NB / 16, 256, 0, stream>>>(Vtg, WoeT, VWt);
  attn_kernel<1><<<ns * 512, 256, 0, stream>>>(Qb, Kb, VWt, weight, maskp, mflag, part, tps);
  attn_kernel<0><<<ns * 512, 256, 0, stream>>>(Qb, Kb, VWt, weight, maskp, mflag, part, tps);
  attn_kernel<2><<<ns * 512, 256, 0, stream>>>(Qb, Kb, VWt, weight, maskp, mflag, part, tps);
  merge_kernel<<<NA / 32, 256, 0, stream>>>(part, boe, (float*)d_out, ns);
}

// Round 23
// 165.261 us; speedup vs baseline: 1.0938x; 1.0498x over previous
//
#include <hip/hip_runtime.h>
#include <hip/hip_bf16.h>

#define NA 8192
#define NB 2048
#define DIM 192
#define NH 4
#define DKH 48
#define TA 16
#define TB 32
#define PREC 204                       // floats per partial record (192 T + 4 l + 4 A + 1 Lw + pad)
#define SCALE 0.14433756729740643f     // 1/sqrt(48)
#define NEGBIG 1e30f

typedef __bf16 bf16x8 __attribute__((ext_vector_type(8)));
typedef float f32x4 __attribute__((ext_vector_type(4)));

#define MFMA16(a, b, c) __builtin_amdgcn_mfma_f32_16x16x32_bf16(a, b, c, 0, 0, 0)

// async global->LDS, 16B per lane, dest = ldsbase + lane*16 (wave-uniform base)
#define GLDS(gp, lp)                                                      \
  __builtin_amdgcn_global_load_lds(                                       \
      (__attribute__((address_space(1))) void*)(const void*)(gp),         \
      (__attribute__((address_space(3))) void*)(void*)(lp), 16, 0, 0)

__device__ __forceinline__ float rsumg(float v) {
  v += __shfl_xor(v, 16, 64);
  v += __shfl_xor(v, 32, 64);
  return v;
}

// ---------------- fused prep: proj + maskdetect + woe ----------------
// blocks [0,1536): Q/K/V projections; 1536: mask detect; [1537,1573): Wo_eff^T
__global__ __launch_bounds__(256) void prep_kernel(
    const float* __restrict__ a_z, const float* __restrict__ bv_z,
    const float* __restrict__ Wq, const float* __restrict__ Wk, const float* __restrict__ Wv,
    const float* __restrict__ bq, const float* __restrict__ bk, const float* __restrict__ bvb,
    const float* __restrict__ Wo, const float* __restrict__ bo,
    const void* __restrict__ maskp,
    __bf16* __restrict__ Qo, __bf16* __restrict__ Ko, __bf16* __restrict__ Vo,
    float* __restrict__ WoeT, float* __restrict__ boe, int* __restrict__ mflag)
{
  const int blk = blockIdx.x;
  const int t = threadIdx.x;

  if (blk < 1536) {
    // ================= proj =================
    __shared__ float xs[8][DIM];
    const float* src; const float* W; const float* bias; int row0; int which;
    if (blk < 1024)      { src = a_z;  W = Wq; bias = bq;  row0 = blk * 8;          which = 0; }
    else if (blk < 1280) { src = bv_z; W = Wk; bias = bk;  row0 = (blk - 1024) * 8; which = 1; }
    else                 { src = bv_z; W = Wv; bias = bvb; row0 = (blk - 1280) * 8; which = 2; }
    for (int i = t; i < 8 * 48; i += 256) {
      int r = i / 48, c = i % 48;
      ((float4*)xs[r])[c] = ((const float4*)(src + (size_t)(row0 + r) * DIM))[c];
    }
    __syncthreads();
    if (t < 192) {
      float acc[8];
      float bb = bias[t];
      #pragma unroll
      for (int r = 0; r < 8; ++r) acc[r] = bb;
      const float4* wr = (const float4*)(W + (size_t)t * DIM);
      for (int c = 0; c < 48; ++c) {
        float4 w = wr[c];
        #pragma unroll
        for (int r = 0; r < 8; ++r) {
          float4 x = ((const float4*)xs[r])[c];
          acc[r] += w.x * x.x + w.y * x.y + w.z * x.z + w.w * x.w;
        }
      }
      int h = t / 48, dd = t % 48;
      if (which == 0) {
        #pragma unroll
        for (int r = 0; r < 8; ++r)
          Qo[((size_t)(row0 + r) * 4 + h) * 64 + dd] = (__bf16)acc[r];
      } else if (which == 1) {
        #pragma unroll
        for (int r = 0; r < 8; ++r)
          Ko[((size_t)h * NB + row0 + r) * 64 + dd] = (__bf16)acc[r];
      } else {
        bf16x8 pk;
        #pragma unroll
        for (int r = 0; r < 8; ++r) pk[r] = (__bf16)acc[r];
        *(bf16x8*)(Vo + (size_t)t * NB + row0) = pk;
      }
    }
    if (which == 0) {
      for (int i = t; i < 512; i += 256) {   // zero the K-pad [48,64)
        int r = i >> 6, hh = (i >> 4) & 3, kk = i & 15;
        Qo[((size_t)(row0 + r) * 4 + hh) * 64 + 48 + kk] = (__bf16)0.f;
      }
    } else if (which == 1) {
      for (int i = t; i < 512; i += 256) {
        int r = i >> 6, hh = (i >> 4) & 3, kk = i & 15;
        Ko[((size_t)hh * NB + row0 + r) * 64 + 48 + kk] = (__bf16)0.f;
      }
    }
  } else if (blk == 1536) {
    // ================= mask detect =================
    __shared__ int fl;
    if (t == 0) fl = 0;
    __syncthreads();
    const unsigned int* mw = (const unsigned int*)maskp;
    for (int i = t; i < 1024; i += 256) {
      unsigned int v = mw[i];
      if (v == 0x3F800000u) atomicMax(&fl, 2);
      else if (v > 1u) atomicMax(&fl, 1);
    }
    __syncthreads();
    if (t == 0) *mflag = fl;
  } else {
    // ================= Wo_eff^T =================
    int i = (blk - 1537) * 256 + t;
    if (i < DIM * DKH) {
      int k = i / DKH, d = i % DKH;
      float s = 0.25f * (Wo[(size_t)d * DIM + k] + Wo[(size_t)(d + 48) * DIM + k] +
                         Wo[(size_t)(d + 96) * DIM + k] + Wo[(size_t)(d + 144) * DIM + k]);
      WoeT[k * DKH + d] = s;
    }
    if (i < DKH) boe[i] = 0.25f * (bo[i] + bo[i + 48] + bo[i + 96] + bo[i + 144]);
  }
}

// ---------------- VW = per-head V @ Woe_h ----------------
__global__ __launch_bounds__(256) void vw_kernel(
    const __bf16* __restrict__ Vt, const float* __restrict__ WoeT, __bf16* __restrict__ VWt)
{
  __shared__ float woe[DIM][DKH];
  const int t = threadIdx.x;
  for (int i = t; i < DIM * DKH / 4; i += 256)
    ((float4*)&woe[0][0])[i] = ((const float4*)WoeT)[i];
  __syncthreads();
  const int b = blockIdx.x * 16 + (t & 15);
  const int grp = t >> 4;
  const int h = grp >> 2;
  const int q = grp & 3;
  float acc[12];
  #pragma unroll
  for (int d = 0; d < 12; ++d) acc[d] = 0.f;
  for (int dp = 0; dp < DKH; ++dp) {
    float v = (float)Vt[(size_t)(h * DKH + dp) * NB + b];
    const float* wrow = &woe[h * DKH + dp][q * 12];
    #pragma unroll
    for (int d = 0; d < 12; ++d) acc[d] += v * wrow[d];
  }
  #pragma unroll
  for (int d = 0; d < 12; ++d)
    VWt[(size_t)(h * DKH + q * 12 + d) * NB + b] = (__bf16)acc[d];
}

// ---------------- fused MFMA attention: ew-factored softmax ----------------
// grid = ns * 512 blocks x 256 threads. Wave = head h. m == 0 fixed reference.
// p_true = exp(qk*SCALE) * ew, ew = mask ? exp(w) : 0.
//   -> QK accumulator seeds ZERO (decoupled from weight convert; masked cols
//      give p = e*0 = 0 exactly); influence term = pt*ew (FMA, no extra exp);
//      Lw = sum(ew) accumulated per split (wstats pass deleted).
// Staging identical to proven R14: K+VW via global_load_lds (wave-private,
// zero barriers), source pre-swizzle, counted vmcnt(4) leaves W(t+1) in flight.
template<int MMODE>
__global__ __launch_bounds__(256, 4) void attn_kernel(
    const __bf16* __restrict__ Qb, const __bf16* __restrict__ Kb, const __bf16* __restrict__ VWt,
    const float* __restrict__ weight, const void* __restrict__ maskp,
    const int* __restrict__ maskflag,
    float* __restrict__ part, int tps)
{
  if (*maskflag != MMODE) return;   // wrong-mode instance: early out (grid-uniform)

  __shared__ __align__(16) __bf16 Kl[4 * 32 * 64];   // 16 KB, swizzled
  __shared__ __align__(16) __bf16 VWl[192 * 32];     // 12 KB, swizzled
  __shared__ __bf16 Ss[4][16][40];                   // 5 KB P staging

  const int t = threadIdx.x;
  const int lane = t & 63;
  const int h = t >> 6;
  const int c = lane & 15;          // actor col
  const int g = lane >> 4;
  const int g8 = g * 8;
  const int s = blockIdx.x >> 9;    // split
  const int a0 = (blockIdx.x & 511) * TA;
  const int tile0 = s * tps;
  const int tend = tile0 + tps;

  const unsigned char* m8 = (const unsigned char*)maskp;
  const float* mfp = (const float*)maskp;
  const int* m32 = (const int*)maskp;

  // Q fragment (B-operand): col a = c, k contiguous
  const __bf16* qp = Qb + ((size_t)(a0 + c) * NH + h) * 64 + g8;
  const bf16x8 qf0 = *(const bf16x8*)qp;
  const bf16x8 qf1 = *(const bf16x8*)(qp + 32);

  float lp = 0.f, Ap = 0.f, Lwp = 0.f;
  f32x4 o0 = {0.f,0.f,0.f,0.f}, o1 = {0.f,0.f,0.f,0.f}, o2 = {0.f,0.f,0.f,0.f};

  const size_t wrow = (size_t)(a0 + c) * NB + g * 4;

  // ---- lane-constant staging geometry (source pre-swizzle; dest linear) ----
  const int kswz = 8 * ((lane & 7) ^ ((lane >> 3) & 7));        // elements
  const int vswz = 8 * ((lane & 3) ^ ((lane >> 3) & 3));        // elements
  const size_t kgrow = (size_t)h * NB + (lane >> 3);            // + b0 per tile
  const size_t vgrow = (size_t)(h * 48 + (lane >> 2)) * NB;     // + b0 per tile
  __bf16* klw = Kl + h * 2048;      // wave's K region (4 KB)
  __bf16* vlw = VWl + h * 1536;     // wave's VW region (3 KB)

  // ---- read-side swizzled fragment offsets (lane-constant) ----
  const int swk  = 8 * (g ^ (c & 7));
  const int swk4 = 8 * ((g | 4) ^ (c & 7));
  const int swv  = 8 * (g ^ ((c >> 1) & 3));
  const __bf16* klr = Kl + h * 2048 + c * 64;
  const __bf16* vlr = VWl + (h * 48 + c) * 32 + swv;

  // ---- raw W prefetch slots (mode-specialized) ----
  float4 nw0, nw1;
  int nmx, nmy;          // mode 1
  int4 nmA, nmB;         // modes 0, 2
  {
    size_t gi = wrow + (size_t)tile0 * TB;
    nw0 = *(const float4*)(weight + gi);
    nw1 = *(const float4*)(weight + gi + 16);
    if constexpr (MMODE == 1)      { nmx = *(const int*)(m8 + gi); nmy = *(const int*)(m8 + gi + 16); }
    else if constexpr (MMODE == 2) { nmA = *(const int4*)(mfp + gi); nmB = *(const int4*)(mfp + gi + 16); }
    else                           { nmA = *(const int4*)(m32 + gi); nmB = *(const int4*)(m32 + gi + 16); }
  }

  for (int tile = tile0; tile < tend; ++tile) {
    const int b0 = tile * TB;

    // [1] stage K(t) 4 + VW(t) 3 -- async, no VGPR destinations
    {
      const __bf16* kg = Kb + (kgrow + b0) * 64 + kswz;
      GLDS(kg,            klw);
      GLDS(kg + 8 * 64,   klw + 512);
      GLDS(kg + 16 * 64,  klw + 1024);
      GLDS(kg + 24 * 64,  klw + 1536);
      const __bf16* vg = VWt + vgrow + b0 + vswz;
      GLDS(vg,            vlw);
      GLDS(vg + 16 * NB,  vlw + 512);
      GLDS(vg + 32 * NB,  vlw + 1024);
    }
    __builtin_amdgcn_sched_barrier(0);

    // [2] convert ew(t) = mask ? exp(w) : 0 (raws issued last body, retired)
    float ew[8];
    if constexpr (MMODE == 1) {
      unsigned ua = (unsigned)nmx, ub = (unsigned)nmy;
      ew[0] = (ua & 0xffu)         ? __expf(nw0.x) : 0.f;
      ew[1] = ((ua >> 8) & 0xffu)  ? __expf(nw0.y) : 0.f;
      ew[2] = ((ua >> 16) & 0xffu) ? __expf(nw0.z) : 0.f;
      ew[3] = (ua >> 24)           ? __expf(nw0.w) : 0.f;
      ew[4] = (ub & 0xffu)         ? __expf(nw1.x) : 0.f;
      ew[5] = ((ub >> 8) & 0xffu)  ? __expf(nw1.y) : 0.f;
      ew[6] = ((ub >> 16) & 0xffu) ? __expf(nw1.z) : 0.f;
      ew[7] = (ub >> 24)           ? __expf(nw1.w) : 0.f;
    } else if constexpr (MMODE == 2) {
      ew[0] = (((unsigned)nmA.x << 1) != 0u) ? __expf(nw0.x) : 0.f;
      ew[1] = (((unsigned)nmA.y << 1) != 0u) ? __expf(nw0.y) : 0.f;
      ew[2] = (((unsigned)nmA.z << 1) != 0u) ? __expf(nw0.z) : 0.f;
      ew[3] = (((unsigned)nmA.w << 1) != 0u) ? __expf(nw0.w) : 0.f;
      ew[4] = (((unsigned)nmB.x << 1) != 0u) ? __expf(nw1.x) : 0.f;
      ew[5] = (((unsigned)nmB.y << 1) != 0u) ? __expf(nw1.y) : 0.f;
      ew[6] = (((unsigned)nmB.z << 1) != 0u) ? __expf(nw1.z) : 0.f;
      ew[7] = (((unsigned)nmB.w << 1) != 0u) ? __expf(nw1.w) : 0.f;
    } else {
      ew[0] = nmA.x ? __expf(nw0.x) : 0.f;
      ew[1] = nmA.y ? __expf(nw0.y) : 0.f;
      ew[2] = nmA.z ? __expf(nw0.z) : 0.f;
      ew[3] = nmA.w ? __expf(nw0.w) : 0.f;
      ew[4] = nmB.x ? __expf(nw1.x) : 0.f;
      ew[5] = nmB.y ? __expf(nw1.y) : 0.f;
      ew[6] = nmB.z ? __expf(nw1.z) : 0.f;
      ew[7] = nmB.w ? __expf(nw1.w) : 0.f;
    }
    __builtin_amdgcn_sched_barrier(0);

    // [3] issue W(t+1) raws (behind stages in FIFO)
    {
      int tn = (tile + 1 < tend) ? tile + 1 : tile;
      size_t gi = wrow + (size_t)tn * TB;
      nw0 = *(const float4*)(weight + gi);
      nw1 = *(const float4*)(weight + gi + 16);
      if constexpr (MMODE == 1)      { nmx = *(const int*)(m8 + gi); nmy = *(const int*)(m8 + gi + 16); }
      else if constexpr (MMODE == 2) { nmA = *(const int4*)(mfp + gi); nmB = *(const int4*)(mfp + gi + 16); }
      else                           { nmA = *(const int4*)(m32 + gi); nmB = *(const int4*)(m32 + gi + 16); }
    }
    __builtin_amdgcn_sched_barrier(0);

    // [4] counted wait: drain the 7 stages, leave W(t+1)'s 4 loads in flight
    asm volatile("s_waitcnt vmcnt(4)" ::: "memory");
    __builtin_amdgcn_sched_barrier(0);

    // [5] QK (seed ZERO -- independent of ew) + softmax + PV
    bf16x8 kA0 = *(const bf16x8*)(klr + swk);
    bf16x8 kA1 = *(const bf16x8*)(klr + swk4);
    bf16x8 kB0 = *(const bf16x8*)(klr + 16 * 64 + swk);
    bf16x8 kB1 = *(const bf16x8*)(klr + 16 * 64 + swk4);
    bf16x8 vf0 = *(const bf16x8*)vlr;
    bf16x8 vf1 = *(const bf16x8*)(vlr + 16 * 32);
    bf16x8 vf2 = *(const bf16x8*)(vlr + 32 * 32);

    f32x4 acc0 = {0.f,0.f,0.f,0.f}, acc1 = {0.f,0.f,0.f,0.f};
    acc0 = MFMA16(kA0, qf0, acc0);
    acc0 = MFMA16(kA1, qf1, acc0);
    acc1 = MFMA16(kB0, qf0, acc1);
    acc1 = MFMA16(kB1, qf1, acc1);

    Lwp += (ew[0] + ew[1]) + (ew[2] + ew[3]) + (ew[4] + ew[5]) + (ew[6] + ew[7]);

    float pt[8];
    #pragma unroll
    for (int j = 0; j < 4; ++j) {
      float e0 = __expf(acc0[j] * SCALE);
      float e1 = __expf(acc1[j] * SCALE);
      float p0 = e0 * ew[j];
      float p1 = e1 * ew[4 + j];
      lp += p0 + p1;
      Ap += p0 * ew[j] + p1 * ew[4 + j];
      pt[j] = p0; pt[4 + j] = p1;
    }

    #pragma unroll
    for (int i = 0; i < 4; ++i) {
      Ss[h][c][g * 4 + i]      = (__bf16)pt[i];
      Ss[h][c][16 + g * 4 + i] = (__bf16)pt[4 + i];
    }
    __builtin_amdgcn_sched_barrier(0);
    bf16x8 pb = *(const bf16x8*)&Ss[h][c][g8];

    o0 = MFMA16(vf0, pb, o0);
    o1 = MFMA16(vf1, pb, o1);
    o2 = MFMA16(vf2, pb, o2);
  }

  // ---- one wave-reduce at the end; write partial record ----
  float l = rsumg(lp);
  float A = rsumg(Ap);
  float Lw = rsumg(Lwp);
  float* pr = part + ((size_t)s * NA + a0 + c) * PREC;
  #pragma unroll
  for (int j = 0; j < 4; ++j) {
    pr[h * 48 + g * 4 + j]      = o0[j];
    pr[h * 48 + 16 + g * 4 + j] = o1[j];
    pr[h * 48 + 32 + g * 4 + j] = o2[j];
  }
  if (g == 0) {
    pr[192 + h] = l;
    pr[196 + h] = A;
    if (h == 0) pr[200] = Lw;
  }
}

// ---------------- merge splits: plain sums (shared m == 0 reference) ----------------
__global__ __launch_bounds__(256) void merge_kernel(
    const float* __restrict__ part, const float* __restrict__ boe,
    float* __restrict__ out, int ns)
{
  __shared__ float fls[32][NH];      // 1/l per (a,h)
  __shared__ float infl[32][NH];
  __shared__ float lws[32];
  const int t = threadIdx.x;
  const int a0 = blockIdx.x * 32;

  if (t < 128) {
    int a = t >> 2, hh = t & 3;
    const float* rec = part + (size_t)(a0 + a) * PREC;
    float lst = 0.f, As = 0.f, Lws = 0.f;
    for (int s = 0; s < ns; ++s) {
      const float* r = rec + (size_t)s * NA * PREC;
      lst += r[192 + hh];
      As  += r[196 + hh];
      if (hh == 0) Lws += r[200];
    }
    float li = 1.f / lst;
    fls[a][hh] = li;
    infl[a][hh] = As * li;
    if (hh == 0) lws[a] = Lws;
  }
  __syncthreads();
  if (t < 32)
    out[(size_t)(a0 + t) * 49 + 48] =
        (infl[t][0] + infl[t][1] + infl[t][2] + infl[t][3]) / (4.f * lws[t]);
  for (int i = t; i < 32 * DKH; i += 256) {
    int a = i / DKH, dd = i - a * DKH;
    float acc = boe[dd];
    const float* rec = part + (size_t)(a0 + a) * PREC;
    for (int s = 0; s < ns; ++s) {
      const float* r = rec + (size_t)s * NA * PREC;
      #pragma unroll
      for (int hh = 0; hh < NH; ++hh)
        acc += fls[a][hh] * r[hh * 48 + dd];
    }
    out[(size_t)(a0 + a) * 49 + dd] = acc;
  }
}

extern "C" void kernel_launch(void* const* d_in, const int* in_sizes, int n_in,
                              void* d_out, int out_size, void* d_ws, size_t ws_size,
                              hipStream_t stream) {
  const float* a_z    = (const float*)d_in[0];
  const float* bv_z   = (const float*)d_in[1];
  const float* weight = (const float*)d_in[2];
  const void*  maskp  = d_in[3];
  const float* Wq = (const float*)d_in[4];
  const float* Wk = (const float*)d_in[5];
  const float* Wv = (const float*)d_in[6];
  const float* Wo = (const float*)d_in[7];
  const float* bq = (const float*)d_in[8];
  const float* bk = (const float*)d_in[9];
  const float* bvb = (const float*)d_in[10];
  const float* bo = (const float*)d_in[11];

  __bf16* Qb  = (__bf16*)d_ws;                      // [NA][4][64]
  __bf16* Kb  = Qb + (size_t)NA * 256;              // [4][NB][64]
  __bf16* Vtg = Kb + (size_t)4 * NB * 64;           // [192][NB]
  __bf16* VWt = Vtg + (size_t)DIM * NB;             // [192][NB]
  float* WoeT = (float*)(VWt + (size_t)DIM * NB);   // [192][48]
  float* boe  = WoeT + DIM * DKH;
  int*  mflag = (int*)(boe + 64);
  float* part = (float*)(mflag + 64);               // [ns][NA][204]

  size_t base = (size_t)((char*)(part) - (char*)d_ws);
  int ns = (ws_size >= base + (size_t)4 * NA * PREC * 4) ? 4 : 2;
  int tps = (NB / TB) / ns;

  prep_kernel<<<1573, 256, 0, stream>>>(a_z, bv_z, Wq, Wk, Wv, bq, bk, bvb, Wo, bo,
                                        maskp, Qb, Kb, Vtg, WoeT, boe, mflag);
  vw_kernel<<<NB / 16, 256, 0, stream>>>(Vtg, WoeT, VWt);
  attn_kernel<1><<<ns * 512, 256, 0, stream>>>(Qb, Kb, VWt, weight, maskp, mflag, part, tps);
  attn_kernel<0><<<ns * 512, 256, 0, stream>>>(Qb, Kb, VWt, weight, maskp, mflag, part, tps);
  attn_kernel<2><<<ns * 512, 256, 0, stream>>>(Qb, Kb, VWt, weight, maskp, mflag, part, tps);
  merge_kernel<<<NA / 32, 256, 0, stream>>>(part, boe, (float*)d_out, ns);
}